// Round 6
// baseline (1627.206 us; speedup 1.0000x reference)
//
#include <hip/hip_runtime.h>
#include <stdint.h>

typedef float  f32x4 __attribute__((ext_vector_type(4)));
typedef int    i32x4 __attribute__((ext_vector_type(4)));
typedef __bf16 bf16x4v __attribute__((ext_vector_type(4)));
typedef __bf16 bf16x8 __attribute__((ext_vector_type(8)));
typedef unsigned short ushort_t;

#define TTOK  16384
#define HDIM  512
#define NEXP  256

// chunked XCD swizzle (grid must be %8==0)
__device__ __forceinline__ int xcdmap(int orig, int G) {
  int q = G >> 3;
  return (orig & 7) * q + (orig >> 3);
}

// global -> LDS direct DMA, 16B per lane. LDS dest wave-uniform base + lane*16;
// global src per-lane (gather / swizzle OK).
__device__ __forceinline__ void gl16(const void* g, void* l) {
  __builtin_amdgcn_global_load_lds(
      (__attribute__((address_space(1))) void*)(uintptr_t)g,
      (__attribute__((address_space(3))) void*)(uint32_t)(uintptr_t)l,
      16, 0, 0);
}

// ---------------- transpose + fp32->bf16 convert: src [R][C] f32 -> dst [C][R] bf16 ----------------
__global__ __launch_bounds__(256) void tconv_kernel(const float* __restrict__ src,
                                                    ushort_t* __restrict__ dst,
                                                    const int R, const int C) {
  __shared__ float t[64][65];
  const int tid = threadIdx.x;
  const int ct = C >> 6;
  const int tr = (int)blockIdx.x / ct, tc = (int)blockIdx.x % ct;
  const size_t mo = (size_t)blockIdx.y * (size_t)R * C;
  const float* s = src + mo + (size_t)(tr * 64) * C + tc * 64;
  __bf16* d = (__bf16*)dst + mo + (size_t)(tc * 64) * R + tr * 64;
  const int r0 = tid >> 4, c0 = (tid & 15) * 4;
  #pragma unroll
  for (int s4 = 0; s4 < 4; ++s4) {
    f32x4 v = *(const f32x4*)(s + (size_t)(r0 + s4 * 16) * C + c0);
    t[r0 + s4 * 16][c0 + 0] = v[0];
    t[r0 + s4 * 16][c0 + 1] = v[1];
    t[r0 + s4 * 16][c0 + 2] = v[2];
    t[r0 + s4 * 16][c0 + 3] = v[3];
  }
  __syncthreads();
  #pragma unroll
  for (int s4 = 0; s4 < 4; ++s4) {
    int oc = r0 + s4 * 16;   // output row within tile = input col
    bf16x4v o = { (__bf16)t[c0 + 0][oc], (__bf16)t[c0 + 1][oc],
                  (__bf16)t[c0 + 2][oc], (__bf16)t[c0 + 3][oc] };
    *(bf16x4v*)(d + (size_t)oc * R + c0) = o;
  }
}

// ---------------- cast x (f32) -> xb (bf16) ----------------
__global__ void cast_kernel(const float* __restrict__ x, ushort_t* __restrict__ xb) {
  size_t i = (size_t)(blockIdx.x * 256 + threadIdx.x) * 8;
  f32x4 a = *(const f32x4*)(x + i);
  f32x4 b = *(const f32x4*)(x + i + 4);
  bf16x4v o0 = { (__bf16)a[0], (__bf16)a[1], (__bf16)a[2], (__bf16)a[3] };
  bf16x4v o1 = { (__bf16)b[0], (__bf16)b[1], (__bf16)b[2], (__bf16)b[3] };
  *(bf16x4v*)((__bf16*)xb + i)     = o0;
  *(bf16x4v*)((__bf16*)xb + i + 4) = o1;
}

// ---------------- router logits: fp32 tiled GEMM (exact) ----------------
__global__ __launch_bounds__(256) void router_kernel(const float* __restrict__ x,
                                                     const float* __restrict__ gw,
                                                     float* __restrict__ logits) {
  __shared__ float xs[64][33];
  __shared__ float gs[64][33];
  const int tid = threadIdx.x;
  const int t0 = blockIdx.x * 64, e0 = blockIdx.y * 64;
  const int tx = tid & 15, ty = tid >> 4;
  const int lrow = tid >> 2, lg = tid & 3;
  const float* xp = x  + (size_t)(t0 + lrow) * HDIM + lg * 8;
  const float* gp = gw + (size_t)(e0 + lrow) * HDIM + lg * 8;
  float acc[4][4] = {};
  for (int k0 = 0; k0 < HDIM; k0 += 32) {
    f32x4 a = *(const f32x4*)(xp + k0);
    f32x4 b = *(const f32x4*)(xp + k0 + 4);
    f32x4 c = *(const f32x4*)(gp + k0);
    f32x4 d = *(const f32x4*)(gp + k0 + 4);
    __syncthreads();
    #pragma unroll
    for (int i = 0; i < 4; ++i) { xs[lrow][lg*8+i] = a[i]; xs[lrow][lg*8+4+i] = b[i]; }
    #pragma unroll
    for (int i = 0; i < 4; ++i) { gs[lrow][lg*8+i] = c[i]; gs[lrow][lg*8+4+i] = d[i]; }
    __syncthreads();
    #pragma unroll
    for (int k = 0; k < 32; ++k) {
      float av[4], bv[4];
      #pragma unroll
      for (int i = 0; i < 4; ++i) av[i] = xs[ty*4+i][k];
      #pragma unroll
      for (int j = 0; j < 4; ++j) bv[j] = gs[tx*4+j][k];
      #pragma unroll
      for (int i = 0; i < 4; ++i)
        #pragma unroll
        for (int j = 0; j < 4; ++j) acc[i][j] += av[i] * bv[j];
    }
  }
  #pragma unroll
  for (int i = 0; i < 4; ++i)
    #pragma unroll
    for (int j = 0; j < 4; ++j)
      logits[(size_t)(t0 + ty*4 + i) * NEXP + e0 + tx*4 + j] = acc[i][j];
}

// ---------------- top-8 + softmax + expert counts ----------------
__global__ __launch_bounds__(256) void topk_kernel(const float* __restrict__ logits,
                                                   int* __restrict__ tk_idx,
                                                   float* __restrict__ tk_w,
                                                   int* __restrict__ ctrl) {
  const int t = blockIdx.x * 4 + (threadIdx.x >> 6);
  const int lane = threadIdx.x & 63;
  const float* lp = logits + (size_t)t * NEXP;
  float v[4];
  #pragma unroll
  for (int j = 0; j < 4; ++j) v[j] = lp[lane + 64*j];
  float mval[8]; int midx[8];
  #pragma unroll
  for (int kk = 0; kk < 8; ++kk) {
    float bv = v[0]; int bj = 0;
    #pragma unroll
    for (int j = 1; j < 4; ++j) if (v[j] > bv) { bv = v[j]; bj = j; }
    unsigned int fb = __float_as_uint(bv);
    fb = (fb & 0x80000000u) ? ~fb : (fb | 0x80000000u);
    int e = lane + 64*bj;
    unsigned long long key = ((unsigned long long)fb << 32) | (unsigned int)(65535 - e);
    #pragma unroll
    for (int o = 32; o > 0; o >>= 1) {
      unsigned long long other = __shfl_xor(key, o);
      if (other > key) key = other;
    }
    int we = 65535 - (int)(key & 0xFFFFFFFFull);
    unsigned int wfb = (unsigned int)(key >> 32);
    unsigned int orig = (wfb & 0x80000000u) ? (wfb & 0x7FFFFFFFu) : ~wfb;
    mval[kk] = __uint_as_float(orig);
    midx[kk] = we;
    if (lane + 64*bj == we) v[bj] = -__builtin_inff();
  }
  float mx = mval[0];
  float w[8], sum = 0.f;
  #pragma unroll
  for (int kk = 0; kk < 8; ++kk) { w[kk] = __expf(mval[kk] - mx); sum += w[kk]; }
  float inv = 1.f / sum;
  #pragma unroll
  for (int kk = 0; kk < 8; ++kk) {
    if (lane == kk) {
      tk_idx[(size_t)t*8 + kk] = midx[kk];
      tk_w [(size_t)t*8 + kk] = w[kk] * inv;
      atomicAdd(&ctrl[midx[kk]], 1);
    }
  }
}

// ---------------- parallel scan + tile table (128-row tiles) ----------------
__global__ __launch_bounds__(256) void scan_kernel(int* __restrict__ ctrl, int* __restrict__ tiles) {
  __shared__ int sn[256], st[256];
  const int e = threadIdx.x;
  const int n = ctrl[e];
  const int tc = (n + 127) >> 7;
  sn[e] = n; st[e] = tc;
  __syncthreads();
  for (int d = 1; d < 256; d <<= 1) {
    int a = 0, b = 0;
    if (e >= d) { a = sn[e - d]; b = st[e - d]; }
    __syncthreads();
    sn[e] += a; st[e] += b;
    __syncthreads();
  }
  ctrl[1024 + e] = sn[e] - n;
  const int tbase = st[e] - tc;
  for (int i = 0; i < tc; ++i) { tiles[2*(tbase+i)] = e; tiles[2*(tbase+i)+1] = i << 7; }
  if (e == 255) { ctrl[512] = st[255]; ctrl[1280] = sn[255]; }
}

// ---------------- scatter (token,slot) -> grouped order ----------------
__global__ void scatter_kernel(const int* __restrict__ tk_idx, const float* __restrict__ tk_w,
                               int* __restrict__ ctrl, int* __restrict__ slot_tok,
                               float* __restrict__ slot_w, int* __restrict__ slot_pos) {
  int i = blockIdx.x * 256 + threadIdx.x;
  int e = tk_idx[i];
  int pos = ctrl[1024 + e] + atomicAdd(&ctrl[256 + e], 1);
  slot_tok[pos] = i >> 3;
  slot_w[pos]   = tk_w[i];
  slot_pos[i]   = pos;
}

// ---------------- SwiGLU GEMM: BM=128, BN=128(U,V), BK=32, dbuf + issue-early ----------------
// W1T/W3T bf16 [e][N][HDIM]. Source-swizzled staging; frag reads slot = lq ^ (row&3).
template<bool GROUPED>
__global__ __launch_bounds__(256, 3)
void swiglu_kernel(const ushort_t* __restrict__ xb,
                   const ushort_t* __restrict__ W1T, const ushort_t* __restrict__ W3T,
                   const int N,
                   const int* __restrict__ ctrl, const int* __restrict__ tiles,
                   const int* __restrict__ slot_tok,
                   ushort_t* __restrict__ outH) {
  const int tid = threadIdx.x;
  const int b = xcdmap(blockIdx.x, gridDim.x);
  int e = 0, nrows = 128, rb, ncol0;
  if (GROUPED) {
    const int tIdx = b >> 2;
    ncol0 = (b & 3) << 7;
    if (tIdx >= ctrl[512]) return;
    e = tiles[2*tIdx];
    const int rs = tiles[2*tIdx + 1];
    nrows = min(128, ctrl[e] - rs);
    rb = ctrl[1024 + e] + rs;
  } else {
    rb = (b & 127) << 7;
    ncol0 = (b >> 7) << 7;
  }

  __shared__ int tokArr[128];
  __shared__ ushort_t lA[2][128*32];
  __shared__ ushort_t lU[2][128*32];
  __shared__ ushort_t lV[2][128*32];

  if (tid < 128) tokArr[tid] = GROUPED ? slot_tok[rb + min(tid, nrows - 1)] : (rb + tid);
  __syncthreads();

  const int lane = tid & 63, wid = tid >> 6;
  const int srow = wid * 32 + (lane >> 2);
  // source-swizzled chunk: LDS slot (lane&3) receives global chunk (lane&3)^(row&3)
  const int ssub = (((lane & 3) ^ ((lane >> 2) & 3))) * 8;
  const size_t eb = GROUPED ? (size_t)e * ((size_t)N * HDIM) : 0;

  const ushort_t* gA0 = xb + (size_t)tokArr[srow]      * HDIM + ssub;
  const ushort_t* gA1 = xb + (size_t)tokArr[srow + 16] * HDIM + ssub;
  const ushort_t* gU0 = W1T + eb + (size_t)(ncol0 + srow)      * HDIM + ssub;
  const ushort_t* gU1 = W1T + eb + (size_t)(ncol0 + srow + 16) * HDIM + ssub;
  const ushort_t* gV0 = W3T + eb + (size_t)(ncol0 + srow)      * HDIM + ssub;
  const ushort_t* gV1 = W3T + eb + (size_t)(ncol0 + srow + 16) * HDIM + ssub;

  const int s0 = (wid * 32)      * 32;   // LDS dest offsets (wave-uniform)
  const int s1 = (wid * 32 + 16) * 32;

  const int wr = (wid >> 1) * 64, wc = (wid & 1) * 64;
  const int lrow = lane & 15, lq = lane >> 4;
  int aoff[4], boff[4];
  #pragma unroll
  for (int i = 0; i < 4; ++i) {
    int row = wr + i*16 + lrow;
    aoff[i] = row * 32 + ((lq ^ (row & 3)) << 3);
  }
  #pragma unroll
  for (int j = 0; j < 4; ++j) {
    int row = wc + j*16 + lrow;
    boff[j] = row * 32 + ((lq ^ (row & 3)) << 3);
  }

  f32x4 aU[4][4], aV[4][4];
  #pragma unroll
  for (int i = 0; i < 4; ++i)
    #pragma unroll
    for (int j = 0; j < 4; ++j) { f32x4 z = {0.f,0.f,0.f,0.f}; aU[i][j] = z; aV[i][j] = z; }

#define SW_STAGE(BUF, KO)                                   \
  { gl16(gA0 + (KO), &lA[BUF][s0]); gl16(gA1 + (KO), &lA[BUF][s1]); \
    gl16(gU0 + (KO), &lU[BUF][s0]); gl16(gU1 + (KO), &lU[BUF][s1]); \
    gl16(gV0 + (KO), &lV[BUF][s0]); gl16(gV1 + (KO), &lV[BUF][s1]); }

  SW_STAGE(0, 0);
  __syncthreads();

  #pragma unroll 1
  for (int ks = 0; ks < HDIM/32; ++ks) {
    const int cur = ks & 1;
    if (ks + 1 < HDIM/32) SW_STAGE(cur ^ 1, (ks + 1) * 32);   // issue-early
    const ushort_t* bA = &lA[cur][0];
    const ushort_t* bU = &lU[cur][0];
    const ushort_t* bV = &lV[cur][0];
    bf16x8 af[4], bu[4], bv[4];
    #pragma unroll
    for (int i = 0; i < 4; ++i) af[i] = *(const bf16x8*)&bA[aoff[i]];
    #pragma unroll
    for (int j = 0; j < 4; ++j) { bu[j] = *(const bf16x8*)&bU[boff[j]]; bv[j] = *(const bf16x8*)&bV[boff[j]]; }
    __builtin_amdgcn_s_setprio(1);
    #pragma unroll
    for (int i = 0; i < 4; ++i)
      #pragma unroll
      for (int j = 0; j < 4; ++j) {
        aU[i][j] = __builtin_amdgcn_mfma_f32_16x16x32_bf16(af[i], bu[j], aU[i][j], 0, 0, 0);
        aV[i][j] = __builtin_amdgcn_mfma_f32_16x16x32_bf16(af[i], bv[j], aV[i][j], 0, 0, 0);
      }
    __builtin_amdgcn_s_setprio(0);
    __syncthreads();   // drains staged loads (latency hidden under compute above)
  }
#undef SW_STAGE

  #pragma unroll
  for (int i = 0; i < 4; ++i)
    #pragma unroll
    for (int j = 0; j < 4; ++j)
      #pragma unroll
      for (int r = 0; r < 4; ++r) {
        int rl = wr + i*16 + lq*4 + r;
        if (rl < nrows) {
          int col = ncol0 + wc + j*16 + lrow;
          float uu = aU[i][j][r], vv = aV[i][j][r];
          float sg = uu / (1.0f + __expf(-uu));
          ((__bf16*)outH)[(size_t)(rb + rl) * N + col] = (__bf16)(sg * vv);
        }
      }
}

// ---------------- GEMM2: BM=128, BN=128, BK=32, dbuf + issue-early; WT bf16 [e][512][K] ----------------
template<bool GROUPED, bool F32OUT>
__global__ __launch_bounds__(256, 4)
void gemm2_kernel(const ushort_t* __restrict__ Asrc,
                  const ushort_t* __restrict__ WT, const int K,
                  const int* __restrict__ ctrl, const int* __restrict__ tiles,
                  const float* __restrict__ slot_w,
                  ushort_t* __restrict__ outBF, float* __restrict__ outF) {
  const int tid = threadIdx.x;
  const int b = xcdmap(blockIdx.x, gridDim.x);
  int e = 0, nrows = 128, rb, ncol0;
  if (GROUPED) {
    const int tIdx = b >> 2;
    ncol0 = (b & 3) << 7;
    if (tIdx >= ctrl[512]) return;
    e = tiles[2*tIdx];
    const int rs = tiles[2*tIdx + 1];
    nrows = min(128, ctrl[e] - rs);
    rb = ctrl[1024 + e] + rs;
  } else {
    rb = (b & 127) << 7;
    ncol0 = (b >> 7) << 7;
  }

  __shared__ ushort_t lA[2][128*32];
  __shared__ ushort_t lW[2][128*32];

  const int lane = tid & 63, wid = tid >> 6;
  const int srow = wid * 32 + (lane >> 2);
  const int ssub = (((lane & 3) ^ ((lane >> 2) & 3))) * 8;
  const size_t eb = GROUPED ? (size_t)e * ((size_t)512 * K) : 0;

  const int ar0 = rb + min(srow,      nrows - 1);
  const int ar1 = rb + min(srow + 16, nrows - 1);
  const ushort_t* gA0 = Asrc + (size_t)ar0 * K + ssub;
  const ushort_t* gA1 = Asrc + (size_t)ar1 * K + ssub;
  const ushort_t* gW0 = WT + eb + (size_t)(ncol0 + srow)      * K + ssub;
  const ushort_t* gW1 = WT + eb + (size_t)(ncol0 + srow + 16) * K + ssub;

  const int s0 = (wid * 32)      * 32;
  const int s1 = (wid * 32 + 16) * 32;

  const int wr = (wid >> 1) * 64, wc = (wid & 1) * 64;
  const int lrow = lane & 15, lq = lane >> 4;
  int aoff[4], boff[4];
  #pragma unroll
  for (int i = 0; i < 4; ++i) {
    int row = wr + i*16 + lrow;
    aoff[i] = row * 32 + ((lq ^ (row & 3)) << 3);
  }
  #pragma unroll
  for (int j = 0; j < 4; ++j) {
    int row = wc + j*16 + lrow;
    boff[j] = row * 32 + ((lq ^ (row & 3)) << 3);
  }

  f32x4 acc[4][4];
  #pragma unroll
  for (int i = 0; i < 4; ++i)
    #pragma unroll
    for (int j = 0; j < 4; ++j) { f32x4 z = {0.f,0.f,0.f,0.f}; acc[i][j] = z; }

#define G2_STAGE(BUF, KO)                                   \
  { gl16(gA0 + (KO), &lA[BUF][s0]); gl16(gA1 + (KO), &lA[BUF][s1]); \
    gl16(gW0 + (KO), &lW[BUF][s0]); gl16(gW1 + (KO), &lW[BUF][s1]); }

  const int ksteps = K >> 5;
  G2_STAGE(0, 0);
  __syncthreads();

  #pragma unroll 1
  for (int ks = 0; ks < ksteps; ++ks) {
    const int cur = ks & 1;
    if (ks + 1 < ksteps) G2_STAGE(cur ^ 1, (ks + 1) * 32);
    const ushort_t* bA = &lA[cur][0];
    const ushort_t* bW = &lW[cur][0];
    bf16x8 af[4], bw[4];
    #pragma unroll
    for (int i = 0; i < 4; ++i) af[i] = *(const bf16x8*)&bA[aoff[i]];
    #pragma unroll
    for (int j = 0; j < 4; ++j) bw[j] = *(const bf16x8*)&bW[boff[j]];
    __builtin_amdgcn_s_setprio(1);
    #pragma unroll
    for (int i = 0; i < 4; ++i)
      #pragma unroll
      for (int j = 0; j < 4; ++j)
        acc[i][j] = __builtin_amdgcn_mfma_f32_16x16x32_bf16(af[i], bw[j], acc[i][j], 0, 0, 0);
    __builtin_amdgcn_s_setprio(0);
    __syncthreads();
  }
#undef G2_STAGE

  #pragma unroll
  for (int i = 0; i < 4; ++i)
    #pragma unroll
    for (int j = 0; j < 4; ++j)
      #pragma unroll
      for (int r = 0; r < 4; ++r) {
        int rl = wr + i*16 + lq*4 + r;
        if (rl < nrows) {
          int col = ncol0 + wc + j*16 + lrow;
          float v = acc[i][j][r];
          if (F32OUT) {
            outF[(size_t)(rb + rl) * 512 + col] = v;
          } else {
            ((__bf16*)outBF)[(size_t)(rb + rl) * 512 + col] = (__bf16)(v * slot_w[rb + rl]);
          }
        }
      }
}

// ---------------- combine ----------------
__global__ __launch_bounds__(256) void combine_kernel(const ushort_t* __restrict__ y_slot,
                                                      const int* __restrict__ slot_pos,
                                                      float* __restrict__ out) {
  const int t = blockIdx.x;
  const int h = threadIdx.x * 2;
  const int* sp = slot_pos + (size_t)t * 8;
  float a0 = 0.f, a1 = 0.f;
  #pragma unroll
  for (int k = 0; k < 8; ++k) {
    int row = sp[k];
    unsigned int u = *(const unsigned int*)(y_slot + (size_t)row * 512 + h);
    a0 += __uint_as_float(u << 16);
    a1 += __uint_as_float(u & 0xFFFF0000u);
  }
  size_t o = (size_t)t * 512 + h;
  out[o]     += a0;
  out[o + 1] += a1;
}

// ---------------- launch ----------------
extern "C" void kernel_launch(void* const* d_in, const int* in_sizes, int n_in,
                              void* d_out, int out_size, void* d_ws, size_t ws_size,
                              hipStream_t stream) {
  (void)in_sizes; (void)n_in; (void)out_size; (void)ws_size;
  const float* x    = (const float*)d_in[0];
  const float* gate = (const float*)d_in[1];
  const float* w1   = (const float*)d_in[2];
  const float* w3   = (const float*)d_in[3];
  const float* w2   = (const float*)d_in[4];
  const float* sw1  = (const float*)d_in[5];
  const float* sw3  = (const float*)d_in[6];
  const float* sw2  = (const float*)d_in[7];
  float* out = (float*)d_out;

  char* ws = (char*)d_ws;
  const size_t MB = (size_t)1 << 20;
  int*   ctrl     = (int*)ws;
  int*   tiles    = (int*)(ws + 8192);
  int*   tk_idx   = (int*)  (ws + 32768);
  float* tk_w     = (float*)(ws + 32768 + 1*524288);
  int*   slot_tok = (int*)  (ws + 32768 + 2*524288);
  float* slot_w   = (float*)(ws + 32768 + 3*524288);
  int*   slot_pos = (int*)  (ws + 32768 + 4*524288);
  float* logits   = (float*)(ws + 4*MB);                 // [4,20) MB
  ushort_t* sw1T  = (ushort_t*)(ws + 20*MB);
  ushort_t* sw3T  = (ushort_t*)(ws + 22*MB);
  ushort_t* sw2T  = (ushort_t*)(ws + 24*MB);
  ushort_t* xb    = (ushort_t*)(ws + 26*MB);             // 16 MB
  ushort_t* hid   = (ushort_t*)(ws + 48*MB);             // 134.2 MB
  ushort_t* w1T   = (ushort_t*)(ws + 184*MB);            // 134.2 MB
  ushort_t* w3T   = (ushort_t*)(ws + 320*MB);            // 134.2 MB
  ushort_t* w2T   = (ushort_t*)(ws + 320*MB);            // overlays w3T (dead after swiglu-g)
  ushort_t* y_slot= (ushort_t*)(ws + 184*MB);            // overlays w1T (dead after swiglu-g)
  ushort_t* hs    = (ushort_t*)(ws + 48*MB);             // overlays hid (dead after gemm2-g)

  hipMemsetAsync(d_ws, 0, 2052, stream);
  // --- weight conversion (transpose to [n][k] bf16) ---
  tconv_kernel<<<dim3(64, 256), 256, 0, stream>>>(w1, w1T, 512, 512);
  tconv_kernel<<<dim3(64, 256), 256, 0, stream>>>(w3, w3T, 512, 512);
  tconv_kernel<<<dim3(176, 1), 256, 0, stream>>>(sw1, sw1T, 512, 1408);
  tconv_kernel<<<dim3(176, 1), 256, 0, stream>>>(sw3, sw3T, 512, 1408);
  tconv_kernel<<<dim3(176, 1), 256, 0, stream>>>(sw2, sw2T, 1408, 512);
  // --- routing chain ---
  cast_kernel<<<4096, 256, 0, stream>>>(x, xb);
  router_kernel<<<dim3(256, 4), 256, 0, stream>>>(x, gate, logits);
  topk_kernel<<<4096, 256, 0, stream>>>(logits, tk_idx, tk_w, ctrl);
  scan_kernel<<<1, 256, 0, stream>>>(ctrl, tiles);
  scatter_kernel<<<512, 256, 0, stream>>>(tk_idx, tk_w, ctrl, slot_tok, slot_w, slot_pos);
  // --- grouped expert FFN ---
  swiglu_kernel<true><<<5120, 256, 0, stream>>>(xb, w1T, w3T, 512, ctrl, tiles, slot_tok, hid);
  tconv_kernel<<<dim3(64, 256), 256, 0, stream>>>(w2, w2T, 512, 512);   // w3T dead now
  gemm2_kernel<true, false><<<5120, 256, 0, stream>>>(hid, w2T, 512, ctrl, tiles, slot_w, y_slot, nullptr);
  // --- shared expert ---
  swiglu_kernel<false><<<1408, 256, 0, stream>>>(xb, sw1T, sw3T, 1408, ctrl, tiles, slot_tok, hs);
  gemm2_kernel<false, true><<<512, 256, 0, stream>>>(hs, sw2T, 1408, ctrl, tiles, slot_w, nullptr, out);
  // --- combine routed + shared ---
  combine_kernel<<<16384, 256, 0, stream>>>(y_slot, slot_pos, out);
}

// Round 7
// 1070.942 us; speedup vs baseline: 1.5194x; 1.5194x over previous
//
#include <hip/hip_runtime.h>
#include <stdint.h>

typedef float  f32x4 __attribute__((ext_vector_type(4)));
typedef int    i32x4 __attribute__((ext_vector_type(4)));
typedef __bf16 bf16x4v __attribute__((ext_vector_type(4)));
typedef __bf16 bf16x8 __attribute__((ext_vector_type(8)));
typedef unsigned short ushort_t;

#define TTOK  16384
#define HDIM  512
#define NEXP  256

// chunked XCD swizzle (grid must be %8==0)
__device__ __forceinline__ int xcdmap(int orig, int G) {
  int q = G >> 3;
  return (orig & 7) * q + (orig >> 3);
}

// global -> LDS direct DMA, 16B per lane. LDS dest wave-uniform base + lane*16;
// global src per-lane (gather OK).
__device__ __forceinline__ void gl16(const void* g, void* l) {
  __builtin_amdgcn_global_load_lds(
      (__attribute__((address_space(1))) void*)(uintptr_t)g,
      (__attribute__((address_space(3))) void*)(uint32_t)(uintptr_t)l,
      16, 0, 0);
}

// ---------------- transpose + fp32->bf16 convert: src [R][C] f32 -> dst [C][R] bf16 ----------------
__global__ __launch_bounds__(256) void tconv_kernel(const float* __restrict__ src,
                                                    ushort_t* __restrict__ dst,
                                                    const int R, const int C) {
  __shared__ float t[64][65];
  const int tid = threadIdx.x;
  const int ct = C >> 6;
  const int tr = (int)blockIdx.x / ct, tc = (int)blockIdx.x % ct;
  const size_t mo = (size_t)blockIdx.y * (size_t)R * C;
  const float* s = src + mo + (size_t)(tr * 64) * C + tc * 64;
  __bf16* d = (__bf16*)dst + mo + (size_t)(tc * 64) * R + tr * 64;
  const int r0 = tid >> 4, c0 = (tid & 15) * 4;
  #pragma unroll
  for (int s4 = 0; s4 < 4; ++s4) {
    f32x4 v = *(const f32x4*)(s + (size_t)(r0 + s4 * 16) * C + c0);
    t[r0 + s4 * 16][c0 + 0] = v[0];
    t[r0 + s4 * 16][c0 + 1] = v[1];
    t[r0 + s4 * 16][c0 + 2] = v[2];
    t[r0 + s4 * 16][c0 + 3] = v[3];
  }
  __syncthreads();
  #pragma unroll
  for (int s4 = 0; s4 < 4; ++s4) {
    int oc = r0 + s4 * 16;
    bf16x4v o = { (__bf16)t[c0 + 0][oc], (__bf16)t[c0 + 1][oc],
                  (__bf16)t[c0 + 2][oc], (__bf16)t[c0 + 3][oc] };
    *(bf16x4v*)(d + (size_t)oc * R + c0) = o;
  }
}

// ---------------- cast x (f32) -> xb (bf16) ----------------
__global__ void cast_kernel(const float* __restrict__ x, ushort_t* __restrict__ xb) {
  size_t i = (size_t)(blockIdx.x * 256 + threadIdx.x) * 8;
  f32x4 a = *(const f32x4*)(x + i);
  f32x4 b = *(const f32x4*)(x + i + 4);
  bf16x4v o0 = { (__bf16)a[0], (__bf16)a[1], (__bf16)a[2], (__bf16)a[3] };
  bf16x4v o1 = { (__bf16)b[0], (__bf16)b[1], (__bf16)b[2], (__bf16)b[3] };
  *(bf16x4v*)((__bf16*)xb + i)     = o0;
  *(bf16x4v*)((__bf16*)xb + i + 4) = o1;
}

// ---------------- router logits: fp32 tiled GEMM (exact) ----------------
__global__ __launch_bounds__(256) void router_kernel(const float* __restrict__ x,
                                                     const float* __restrict__ gw,
                                                     float* __restrict__ logits) {
  __shared__ float xs[64][33];
  __shared__ float gs[64][33];
  const int tid = threadIdx.x;
  const int t0 = blockIdx.x * 64, e0 = blockIdx.y * 64;
  const int tx = tid & 15, ty = tid >> 4;
  const int lrow = tid >> 2, lg = tid & 3;
  const float* xp = x  + (size_t)(t0 + lrow) * HDIM + lg * 8;
  const float* gp = gw + (size_t)(e0 + lrow) * HDIM + lg * 8;
  float acc[4][4] = {};
  for (int k0 = 0; k0 < HDIM; k0 += 32) {
    f32x4 a = *(const f32x4*)(xp + k0);
    f32x4 b = *(const f32x4*)(xp + k0 + 4);
    f32x4 c = *(const f32x4*)(gp + k0);
    f32x4 d = *(const f32x4*)(gp + k0 + 4);
    __syncthreads();
    #pragma unroll
    for (int i = 0; i < 4; ++i) { xs[lrow][lg*8+i] = a[i]; xs[lrow][lg*8+4+i] = b[i]; }
    #pragma unroll
    for (int i = 0; i < 4; ++i) { gs[lrow][lg*8+i] = c[i]; gs[lrow][lg*8+4+i] = d[i]; }
    __syncthreads();
    #pragma unroll
    for (int k = 0; k < 32; ++k) {
      float av[4], bv[4];
      #pragma unroll
      for (int i = 0; i < 4; ++i) av[i] = xs[ty*4+i][k];
      #pragma unroll
      for (int j = 0; j < 4; ++j) bv[j] = gs[tx*4+j][k];
      #pragma unroll
      for (int i = 0; i < 4; ++i)
        #pragma unroll
        for (int j = 0; j < 4; ++j) acc[i][j] += av[i] * bv[j];
    }
  }
  #pragma unroll
  for (int i = 0; i < 4; ++i)
    #pragma unroll
    for (int j = 0; j < 4; ++j)
      logits[(size_t)(t0 + ty*4 + i) * NEXP + e0 + tx*4 + j] = acc[i][j];
}

// ---------------- top-8 + softmax + expert counts ----------------
__global__ __launch_bounds__(256) void topk_kernel(const float* __restrict__ logits,
                                                   int* __restrict__ tk_idx,
                                                   float* __restrict__ tk_w,
                                                   int* __restrict__ ctrl) {
  const int t = blockIdx.x * 4 + (threadIdx.x >> 6);
  const int lane = threadIdx.x & 63;
  const float* lp = logits + (size_t)t * NEXP;
  float v[4];
  #pragma unroll
  for (int j = 0; j < 4; ++j) v[j] = lp[lane + 64*j];
  float mval[8]; int midx[8];
  #pragma unroll
  for (int kk = 0; kk < 8; ++kk) {
    float bv = v[0]; int bj = 0;
    #pragma unroll
    for (int j = 1; j < 4; ++j) if (v[j] > bv) { bv = v[j]; bj = j; }
    unsigned int fb = __float_as_uint(bv);
    fb = (fb & 0x80000000u) ? ~fb : (fb | 0x80000000u);
    int e = lane + 64*bj;
    unsigned long long key = ((unsigned long long)fb << 32) | (unsigned int)(65535 - e);
    #pragma unroll
    for (int o = 32; o > 0; o >>= 1) {
      unsigned long long other = __shfl_xor(key, o);
      if (other > key) key = other;
    }
    int we = 65535 - (int)(key & 0xFFFFFFFFull);
    unsigned int wfb = (unsigned int)(key >> 32);
    unsigned int orig = (wfb & 0x80000000u) ? (wfb & 0x7FFFFFFFu) : ~wfb;
    mval[kk] = __uint_as_float(orig);
    midx[kk] = we;
    if (lane + 64*bj == we) v[bj] = -__builtin_inff();
  }
  float mx = mval[0];
  float w[8], sum = 0.f;
  #pragma unroll
  for (int kk = 0; kk < 8; ++kk) { w[kk] = __expf(mval[kk] - mx); sum += w[kk]; }
  float inv = 1.f / sum;
  #pragma unroll
  for (int kk = 0; kk < 8; ++kk) {
    if (lane == kk) {
      tk_idx[(size_t)t*8 + kk] = midx[kk];
      tk_w [(size_t)t*8 + kk] = w[kk] * inv;
      atomicAdd(&ctrl[midx[kk]], 1);
    }
  }
}

// ---------------- parallel scan + tile table (128-row tiles) ----------------
__global__ __launch_bounds__(256) void scan_kernel(int* __restrict__ ctrl, int* __restrict__ tiles) {
  __shared__ int sn[256], st[256];
  const int e = threadIdx.x;
  const int n = ctrl[e];
  const int tc = (n + 127) >> 7;
  sn[e] = n; st[e] = tc;
  __syncthreads();
  for (int d = 1; d < 256; d <<= 1) {
    int a = 0, b = 0;
    if (e >= d) { a = sn[e - d]; b = st[e - d]; }
    __syncthreads();
    sn[e] += a; st[e] += b;
    __syncthreads();
  }
  ctrl[1024 + e] = sn[e] - n;
  const int tbase = st[e] - tc;
  for (int i = 0; i < tc; ++i) { tiles[2*(tbase+i)] = e; tiles[2*(tbase+i)+1] = i << 7; }
  if (e == 255) { ctrl[512] = st[255]; ctrl[1280] = sn[255]; }
}

// ---------------- scatter (token,slot) -> grouped order ----------------
__global__ void scatter_kernel(const int* __restrict__ tk_idx, const float* __restrict__ tk_w,
                               int* __restrict__ ctrl, int* __restrict__ slot_tok,
                               float* __restrict__ slot_w, int* __restrict__ slot_pos) {
  int i = blockIdx.x * 256 + threadIdx.x;
  int e = tk_idx[i];
  int pos = ctrl[1024 + e] + atomicAdd(&ctrl[256 + e], 1);
  slot_tok[pos] = i >> 3;
  slot_w[pos]   = tk_w[i];
  slot_pos[i]   = pos;
}

// ---------------- SwiGLU GEMM: BM=128, BN=128(U,V), BK=32, dbuf + counted vmcnt ----------------
template<bool GROUPED>
__global__ __launch_bounds__(256, 2)
void swiglu_kernel(const ushort_t* __restrict__ xb,
                   const ushort_t* __restrict__ W1T, const ushort_t* __restrict__ W3T,
                   const int N,
                   const int* __restrict__ ctrl, const int* __restrict__ tiles,
                   const int* __restrict__ slot_tok,
                   ushort_t* __restrict__ outH) {
  const int tid = threadIdx.x;
  const int b = xcdmap(blockIdx.x, gridDim.x);
  int e = 0, nrows = 128, rb, ncol0;
  if (GROUPED) {
    const int tIdx = b >> 2;
    ncol0 = (b & 3) << 7;
    if (tIdx >= ctrl[512]) return;
    e = tiles[2*tIdx];
    const int rs = tiles[2*tIdx + 1];
    nrows = min(128, ctrl[e] - rs);
    rb = ctrl[1024 + e] + rs;
  } else {
    rb = (b & 127) << 7;
    ncol0 = (b >> 7) << 7;
  }

  __shared__ int tokArr[128];
  __shared__ ushort_t lA[2][128*32];
  __shared__ ushort_t lU[2][128*32];
  __shared__ ushort_t lV[2][128*32];

  if (tid < 128) tokArr[tid] = GROUPED ? slot_tok[rb + min(tid, nrows - 1)] : (rb + tid);
  __syncthreads();

  const int lane = tid & 63, wid = tid >> 6;
  const int srow = wid * 32 + (lane >> 2);
  const int ssub = (lane & 3) * 8;
  const size_t eb = GROUPED ? (size_t)e * ((size_t)N * HDIM) : 0;

  const ushort_t* gA0 = xb + (size_t)tokArr[srow]      * HDIM + ssub;
  const ushort_t* gA1 = xb + (size_t)tokArr[srow + 16] * HDIM + ssub;
  const ushort_t* gU0 = W1T + eb + (size_t)(ncol0 + srow)      * HDIM + ssub;
  const ushort_t* gU1 = W1T + eb + (size_t)(ncol0 + srow + 16) * HDIM + ssub;
  const ushort_t* gV0 = W3T + eb + (size_t)(ncol0 + srow)      * HDIM + ssub;
  const ushort_t* gV1 = W3T + eb + (size_t)(ncol0 + srow + 16) * HDIM + ssub;

  const int s0 = (wid * 32)      * 32;
  const int s1 = (wid * 32 + 16) * 32;

  const int wr = (wid >> 1) * 64, wc = (wid & 1) * 64;
  const int lrow = lane & 15, lq = lane >> 4;
  int aoff[4], boff[4];
  #pragma unroll
  for (int i = 0; i < 4; ++i) aoff[i] = (wr + i*16 + lrow) * 32 + lq * 8;
  #pragma unroll
  for (int j = 0; j < 4; ++j) boff[j] = (wc + j*16 + lrow) * 32 + lq * 8;

  f32x4 aU[4][4], aV[4][4];
  #pragma unroll
  for (int i = 0; i < 4; ++i)
    #pragma unroll
    for (int j = 0; j < 4; ++j) { f32x4 z = {0.f,0.f,0.f,0.f}; aU[i][j] = z; aV[i][j] = z; }

#define SW_STAGE(BUF, KO)                                   \
  { gl16(gA0 + (KO), &lA[BUF][s0]); gl16(gA1 + (KO), &lA[BUF][s1]); \
    gl16(gU0 + (KO), &lU[BUF][s0]); gl16(gU1 + (KO), &lU[BUF][s1]); \
    gl16(gV0 + (KO), &lV[BUF][s0]); gl16(gV1 + (KO), &lV[BUF][s1]); }

  SW_STAGE(0, 0);

  #pragma unroll 1
  for (int ks = 0; ks < HDIM/32; ++ks) {
    const int cur = ks & 1;
    if (ks + 1 < HDIM/32) {
      SW_STAGE(cur ^ 1, (ks + 1) * 32);                // prefetch next tile
      asm volatile("s_waitcnt vmcnt(6)" ::: "memory"); // wait only current tile's 6
    } else {
      asm volatile("s_waitcnt vmcnt(0)" ::: "memory");
    }
    __builtin_amdgcn_s_barrier();                      // all waves' cur-tile staged
    asm volatile("" ::: "memory");
    const ushort_t* bA = &lA[cur][0];
    const ushort_t* bU = &lU[cur][0];
    const ushort_t* bV = &lV[cur][0];
    bf16x8 af[4], bu[4], bv[4];
    #pragma unroll
    for (int i = 0; i < 4; ++i) af[i] = *(const bf16x8*)&bA[aoff[i]];
    #pragma unroll
    for (int j = 0; j < 4; ++j) { bu[j] = *(const bf16x8*)&bU[boff[j]]; bv[j] = *(const bf16x8*)&bV[boff[j]]; }
    __builtin_amdgcn_s_setprio(1);
    #pragma unroll
    for (int i = 0; i < 4; ++i)
      #pragma unroll
      for (int j = 0; j < 4; ++j) {
        aU[i][j] = __builtin_amdgcn_mfma_f32_16x16x32_bf16(af[i], bu[j], aU[i][j], 0, 0, 0);
        aV[i][j] = __builtin_amdgcn_mfma_f32_16x16x32_bf16(af[i], bv[j], aV[i][j], 0, 0, 0);
      }
    __builtin_amdgcn_s_setprio(0);
    asm volatile("" ::: "memory");
    __builtin_amdgcn_s_barrier();                      // done reading cur before overwrite
  }
#undef SW_STAGE

  #pragma unroll
  for (int i = 0; i < 4; ++i)
    #pragma unroll
    for (int j = 0; j < 4; ++j)
      #pragma unroll
      for (int r = 0; r < 4; ++r) {
        int rl = wr + i*16 + lq*4 + r;
        if (rl < nrows) {
          int col = ncol0 + wc + j*16 + lrow;
          float uu = aU[i][j][r], vv = aV[i][j][r];
          float sg = uu / (1.0f + __expf(-uu));
          ((__bf16*)outH)[(size_t)(rb + rl) * N + col] = (__bf16)(sg * vv);
        }
      }
}

// ---------------- GEMM2: BM=128, BN=128, BK=32, dbuf + counted vmcnt; WT bf16 [e][512][K] ----------------
template<bool GROUPED, bool F32OUT>
__global__ __launch_bounds__(256, 3)
void gemm2_kernel(const ushort_t* __restrict__ Asrc,
                  const ushort_t* __restrict__ WT, const int K,
                  const int* __restrict__ ctrl, const int* __restrict__ tiles,
                  const float* __restrict__ slot_w,
                  ushort_t* __restrict__ outBF, float* __restrict__ outF) {
  const int tid = threadIdx.x;
  const int b = xcdmap(blockIdx.x, gridDim.x);
  int e = 0, nrows = 128, rb, ncol0;
  if (GROUPED) {
    const int tIdx = b >> 2;
    ncol0 = (b & 3) << 7;
    if (tIdx >= ctrl[512]) return;
    e = tiles[2*tIdx];
    const int rs = tiles[2*tIdx + 1];
    nrows = min(128, ctrl[e] - rs);
    rb = ctrl[1024 + e] + rs;
  } else {
    rb = (b & 127) << 7;
    ncol0 = (b >> 7) << 7;
  }

  __shared__ ushort_t lA[2][128*32];
  __shared__ ushort_t lW[2][128*32];

  const int lane = tid & 63, wid = tid >> 6;
  const int srow = wid * 32 + (lane >> 2);
  const int ssub = (lane & 3) * 8;
  const size_t eb = GROUPED ? (size_t)e * ((size_t)512 * K) : 0;

  const int ar0 = rb + min(srow,      nrows - 1);
  const int ar1 = rb + min(srow + 16, nrows - 1);
  const ushort_t* gA0 = Asrc + (size_t)ar0 * K + ssub;
  const ushort_t* gA1 = Asrc + (size_t)ar1 * K + ssub;
  const ushort_t* gW0 = WT + eb + (size_t)(ncol0 + srow)      * K + ssub;
  const ushort_t* gW1 = WT + eb + (size_t)(ncol0 + srow + 16) * K + ssub;

  const int s0 = (wid * 32)      * 32;
  const int s1 = (wid * 32 + 16) * 32;

  const int wr = (wid >> 1) * 64, wc = (wid & 1) * 64;
  const int lrow = lane & 15, lq = lane >> 4;
  int aoff[4], boff[4];
  #pragma unroll
  for (int i = 0; i < 4; ++i) aoff[i] = (wr + i*16 + lrow) * 32 + lq * 8;
  #pragma unroll
  for (int j = 0; j < 4; ++j) boff[j] = (wc + j*16 + lrow) * 32 + lq * 8;

  f32x4 acc[4][4];
  #pragma unroll
  for (int i = 0; i < 4; ++i)
    #pragma unroll
    for (int j = 0; j < 4; ++j) { f32x4 z = {0.f,0.f,0.f,0.f}; acc[i][j] = z; }

#define G2_STAGE(BUF, KO)                                   \
  { gl16(gA0 + (KO), &lA[BUF][s0]); gl16(gA1 + (KO), &lA[BUF][s1]); \
    gl16(gW0 + (KO), &lW[BUF][s0]); gl16(gW1 + (KO), &lW[BUF][s1]); }

  const int ksteps = K >> 5;
  G2_STAGE(0, 0);

  #pragma unroll 1
  for (int ks = 0; ks < ksteps; ++ks) {
    const int cur = ks & 1;
    if (ks + 1 < ksteps) {
      G2_STAGE(cur ^ 1, (ks + 1) * 32);
      asm volatile("s_waitcnt vmcnt(4)" ::: "memory");
    } else {
      asm volatile("s_waitcnt vmcnt(0)" ::: "memory");
    }
    __builtin_amdgcn_s_barrier();
    asm volatile("" ::: "memory");
    const ushort_t* bA = &lA[cur][0];
    const ushort_t* bW = &lW[cur][0];
    bf16x8 af[4], bw[4];
    #pragma unroll
    for (int i = 0; i < 4; ++i) af[i] = *(const bf16x8*)&bA[aoff[i]];
    #pragma unroll
    for (int j = 0; j < 4; ++j) bw[j] = *(const bf16x8*)&bW[boff[j]];
    __builtin_amdgcn_s_setprio(1);
    #pragma unroll
    for (int i = 0; i < 4; ++i)
      #pragma unroll
      for (int j = 0; j < 4; ++j)
        acc[i][j] = __builtin_amdgcn_mfma_f32_16x16x32_bf16(af[i], bw[j], acc[i][j], 0, 0, 0);
    __builtin_amdgcn_s_setprio(0);
    asm volatile("" ::: "memory");
    __builtin_amdgcn_s_barrier();
  }
#undef G2_STAGE

  #pragma unroll
  for (int i = 0; i < 4; ++i)
    #pragma unroll
    for (int j = 0; j < 4; ++j)
      #pragma unroll
      for (int r = 0; r < 4; ++r) {
        int rl = wr + i*16 + lq*4 + r;
        if (rl < nrows) {
          int col = ncol0 + wc + j*16 + lrow;
          float v = acc[i][j][r];
          if (F32OUT) {
            outF[(size_t)(rb + rl) * 512 + col] = v;
          } else {
            ((__bf16*)outBF)[(size_t)(rb + rl) * 512 + col] = (__bf16)(v * slot_w[rb + rl]);
          }
        }
      }
}

// ---------------- combine ----------------
__global__ __launch_bounds__(256) void combine_kernel(const ushort_t* __restrict__ y_slot,
                                                      const int* __restrict__ slot_pos,
                                                      float* __restrict__ out) {
  const int t = blockIdx.x;
  const int h = threadIdx.x * 2;
  const int* sp = slot_pos + (size_t)t * 8;
  float a0 = 0.f, a1 = 0.f;
  #pragma unroll
  for (int k = 0; k < 8; ++k) {
    int row = sp[k];
    unsigned int u = *(const unsigned int*)(y_slot + (size_t)row * 512 + h);
    a0 += __uint_as_float(u << 16);
    a1 += __uint_as_float(u & 0xFFFF0000u);
  }
  size_t o = (size_t)t * 512 + h;
  out[o]     += a0;
  out[o + 1] += a1;
}

// ---------------- launch ----------------
extern "C" void kernel_launch(void* const* d_in, const int* in_sizes, int n_in,
                              void* d_out, int out_size, void* d_ws, size_t ws_size,
                              hipStream_t stream) {
  (void)in_sizes; (void)n_in; (void)out_size; (void)ws_size;
  const float* x    = (const float*)d_in[0];
  const float* gate = (const float*)d_in[1];
  const float* w1   = (const float*)d_in[2];
  const float* w3   = (const float*)d_in[3];
  const float* w2   = (const float*)d_in[4];
  const float* sw1  = (const float*)d_in[5];
  const float* sw3  = (const float*)d_in[6];
  const float* sw2  = (const float*)d_in[7];
  float* out = (float*)d_out;

  char* ws = (char*)d_ws;
  const size_t MB = (size_t)1 << 20;
  int*   ctrl     = (int*)ws;
  int*   tiles    = (int*)(ws + 8192);
  int*   tk_idx   = (int*)  (ws + 32768);
  float* tk_w     = (float*)(ws + 32768 + 1*524288);
  int*   slot_tok = (int*)  (ws + 32768 + 2*524288);
  float* slot_w   = (float*)(ws + 32768 + 3*524288);
  int*   slot_pos = (int*)  (ws + 32768 + 4*524288);
  float* logits   = (float*)(ws + 4*MB);                 // [4,20) MB
  ushort_t* sw1T  = (ushort_t*)(ws + 20*MB);
  ushort_t* sw3T  = (ushort_t*)(ws + 22*MB);
  ushort_t* sw2T  = (ushort_t*)(ws + 24*MB);
  ushort_t* xb    = (ushort_t*)(ws + 26*MB);             // 16 MB
  ushort_t* hid   = (ushort_t*)(ws + 48*MB);             // 134.2 MB
  ushort_t* w1T   = (ushort_t*)(ws + 184*MB);            // 134.2 MB
  ushort_t* w3T   = (ushort_t*)(ws + 320*MB);            // 134.2 MB
  ushort_t* w2T   = (ushort_t*)(ws + 320*MB);            // overlays w3T (dead after swiglu-g)
  ushort_t* y_slot= (ushort_t*)(ws + 184*MB);            // overlays w1T (dead after swiglu-g)
  ushort_t* hs    = (ushort_t*)(ws + 48*MB);             // overlays hid (dead after gemm2-g)

  hipMemsetAsync(d_ws, 0, 2052, stream);
  // --- weight conversion (transpose to [n][k] bf16) ---
  tconv_kernel<<<dim3(64, 256), 256, 0, stream>>>(w1, w1T, 512, 512);
  tconv_kernel<<<dim3(64, 256), 256, 0, stream>>>(w3, w3T, 512, 512);
  tconv_kernel<<<dim3(176, 1), 256, 0, stream>>>(sw1, sw1T, 512, 1408);
  tconv_kernel<<<dim3(176, 1), 256, 0, stream>>>(sw3, sw3T, 512, 1408);
  tconv_kernel<<<dim3(176, 1), 256, 0, stream>>>(sw2, sw2T, 1408, 512);
  // --- routing chain ---
  cast_kernel<<<4096, 256, 0, stream>>>(x, xb);
  router_kernel<<<dim3(256, 4), 256, 0, stream>>>(x, gate, logits);
  topk_kernel<<<4096, 256, 0, stream>>>(logits, tk_idx, tk_w, ctrl);
  scan_kernel<<<1, 256, 0, stream>>>(ctrl, tiles);
  scatter_kernel<<<512, 256, 0, stream>>>(tk_idx, tk_w, ctrl, slot_tok, slot_w, slot_pos);
  // --- grouped expert FFN ---
  swiglu_kernel<true><<<5120, 256, 0, stream>>>(xb, w1T, w3T, 512, ctrl, tiles, slot_tok, hid);
  tconv_kernel<<<dim3(64, 256), 256, 0, stream>>>(w2, w2T, 512, 512);   // w3T dead now
  gemm2_kernel<true, false><<<5120, 256, 0, stream>>>(hid, w2T, 512, ctrl, tiles, slot_w, y_slot, nullptr);
  // --- shared expert ---
  swiglu_kernel<false><<<1408, 256, 0, stream>>>(xb, sw1T, sw3T, 1408, ctrl, tiles, slot_tok, hs);
  gemm2_kernel<false, true><<<512, 256, 0, stream>>>(hs, sw2T, 1408, ctrl, tiles, slot_w, nullptr, out);
  // --- combine routed + shared ---
  combine_kernel<<<16384, 256, 0, stream>>>(y_slot, slot_pos, out);
}